// Round 5
// baseline (81.636 us; speedup 1.0000x reference)
//
#include <hip/hip_runtime.h>
#include <hip/hip_bf16.h>

// Problem constants (JointAnfisNet)
#define BATCH      16384
#define N_IN       6
#define N_MF       5
#define N_FUZZ     30      // N_IN * N_MF
#define N_RULES    2048
#define N_OUT_MEM  12

// Decomposition: 256 rows/block, 4 rows per lane packed as f16x4 (uint2) ->
// one ds_read_b64 serves 4 rows. Rules split 8 ways; grid = 512 blocks,
// 2 blocks/CU (LDS 63KB, VGPR<=64 via launch_bounds).
// R5 changes vs R4 (80.0us) -- de-serialize block start/tail, rule loop kept
// byte-identical:
//   1) probe: branch-free (15 independent loads, one latency round), computed
//      per-thread (uniform) -> no shared flag, no barrier, no lane-0 chain.
//   2) x staging phase removed: fuzzify reads x directly from global (6KB
//      window, 5x reuse, L1-hot) and computes (c,1/s) inline -> two fewer
//      barriers, one fewer phase.
//   3) reduce tail uses 768 threads via unified pacc[WAVES][3][ROWS_PB].
//   4) finalize at 128x128 (was 64x256) to spread latency across more CUs.
#define ROWS_PB    256
#define SPLITS     8
#define RULES_PB   (N_RULES / SPLITS)     // 256
#define THREADS    1024
#define WAVES      16
#define RULES_PW   (RULES_PB / WAVES)     // 16
#define ROWGROUPS  (BATCH / ROWS_PB)      // 64

// d_ws layout: partials f32[SPLITS*3*BATCH] = 1.5 MB
#define WS_PART_OFF    0

typedef _Float16 f16x2 __attribute__((ext_vector_type(2)));

// ---------------------------------------------------------------------------
// Deterministic dtype probe: mf_scales is genuinely in [0.5, 1.5]. Interpret
// its first 60 bytes as 30 bf16 halves; all-in-[0.4,1.6] => bf16 data.
// Branch-free: all 15 dwords load independently (single latency round).
// ---------------------------------------------------------------------------
__device__ inline int probe_is_bf16(const void* mfs) {
    const unsigned int* w = (const unsigned int*)mfs;
    unsigned int v[15];
#pragma unroll
    for (int k = 0; k < 15; ++k) v[k] = w[k];
    int ok = 1;
#pragma unroll
    for (int k = 0; k < 15; ++k) {
        const float lo = __uint_as_float(v[k] << 16);
        const float hi = __uint_as_float(v[k] & 0xffff0000u);
        ok &= (lo >= 0.4f && lo <= 1.6f && hi >= 0.4f && hi <= 1.6f) ? 1 : 0;
    }
    return ok;
}

// ---------------------------------------------------------------------------
// Main: block = (row group g: 256 rows) x (rule split s: 256 rules).
//   lane (0..63) covers rows {l, l+64, l+128, l+192} packed as f16x4 in uint2.
//   wave (0..15) handles 16 rules, metadata inline-loaded by lanes 0..15 and
//   broadcast via readlane at constant j. Inner loop: ONLY ds_read_b64.
// ---------------------------------------------------------------------------
__global__ __launch_bounds__(THREADS, 8)
void anfis_main(const void* __restrict__ x_,
                const void* __restrict__ mfc_,
                const void* __restrict__ mfs_,
                const void* __restrict__ oc_,
                const int* __restrict__ input_rules,
                const int* __restrict__ output_rules,
                float* __restrict__ partials) {
    __shared__ uint2 fuzz4[N_FUZZ][64];            // 15 KB, 4 rows/lane f16x4
    __shared__ float pacc[WAVES][3][ROWS_PB];      // 48 KB reduce arena

    const int t     = threadIdx.x;
    const int g     = blockIdx.x >> 3;             // row group 0..63
    const int split = blockIdx.x & 7;              // rule split 0..7
    const int row0  = g * ROWS_PB;

    const bool is_bf16 = (probe_is_bf16(mfs_) != 0);   // uniform across block

    // ---- per-lane rule-metadata inline load+pack (overlaps fuzzify loads) --
    const int lane = t & 63;
    const int wave = __builtin_amdgcn_readfirstlane(t >> 6);
    const int rbase = split * RULES_PB + wave * RULES_PW;
    unsigned pk_v = 0u;
    float owx_v = 0.0f, owy_v = 0.0f;
    if (lane < RULES_PW) {
        const int r = rbase + lane;
        const int* rp = input_rules + r * N_IN;    // contiguous window per wave
        unsigned p = 0;
#pragma unroll
        for (int i = 0; i < N_IN; ++i) p |= ((unsigned)rp[i] & 31u) << (5 * i);
        pk_v = p;
        const int o0i = output_rules[2 * r + 0];
        const int o1i = output_rules[2 * r + 1];
        if (is_bf16) {
            const unsigned short* oc = (const unsigned short*)oc_;
            owx_v = __uint_as_float((unsigned)oc[o0i] << 16);
            owy_v = __uint_as_float((unsigned)oc[o1i] << 16);
        } else {
            const float* oc = (const float*)oc_;
            owx_v = oc[o0i]; owy_v = oc[o1i];
        }
    }

    // ---- fuzzify straight from global: 30 x 64 uint2, 4 rows' exp(-z^2) ----
    for (int e = t; e < N_FUZZ * 64; e += THREADS) {
        const int v  = e >> 6;      // MF value index 0..29
        const int ln = e & 63;
        const int i  = v / N_MF;    // input index
        float c, s;
        if (is_bf16) {
            c = __uint_as_float((unsigned)((const unsigned short*)mfc_)[v] << 16);
            s = __uint_as_float((unsigned)((const unsigned short*)mfs_)[v] << 16);
        } else {
            c = ((const float*)mfc_)[v];
            s = ((const float*)mfs_)[v];
        }
        const float sinv = 1.0f / s;
        float f[4];
#pragma unroll
        for (int k = 0; k < 4; ++k) {
            const int row = row0 + ln + 64 * k;
            float xv;
            if (is_bf16) {
                xv = __uint_as_float(
                    (unsigned)((const unsigned short*)x_)[row * N_IN + i] << 16);
            } else {
                xv = ((const float*)x_)[row * N_IN + i];
            }
            const float z = (xv - c) * sinv;
            f[k] = __expf(-z * z);
        }
        f16x2 a = { (_Float16)f[0], (_Float16)f[1] };   // rows ln, ln+64
        f16x2 b = { (_Float16)f[2], (_Float16)f[3] };   // rows ln+128, +192
        uint2 u;
        u.x = __builtin_bit_cast(unsigned int, a);
        u.y = __builtin_bit_cast(unsigned int, b);
        fuzz4[v][ln] = u;
    }
    __syncthreads();

    // ---- rule loop: readlane-broadcast metadata, 6 ds_read_b64 gathers ----
    const uint2* fz = &fuzz4[0][0];

    float l1[4] = {0.f, 0.f, 0.f, 0.f};
    float d0[4] = {0.f, 0.f, 0.f, 0.f};
    float d1[4] = {0.f, 0.f, 0.f, 0.f};

#pragma unroll
    for (int j = 0; j < RULES_PW; ++j) {
        // compile-time lane j -> v_readlane to SGPR; no memory op, no lgkmcnt
        const unsigned p = (unsigned)__builtin_amdgcn_readlane((int)pk_v, j);
        const float ox = __uint_as_float(
            (unsigned)__builtin_amdgcn_readlane((int)__float_as_uint(owx_v), j));
        const float oy = __uint_as_float(
            (unsigned)__builtin_amdgcn_readlane((int)__float_as_uint(owy_v), j));

        const uint2 g0 = fz[((p      ) & 31u) * 64 + lane];
        const uint2 g1 = fz[((p >> 5 ) & 31u) * 64 + lane];
        const uint2 g2 = fz[((p >> 10) & 31u) * 64 + lane];
        const uint2 g3 = fz[((p >> 15) & 31u) * 64 + lane];
        const uint2 g4 = fz[((p >> 20) & 31u) * 64 + lane];
        const uint2 g5 = fz[((p >> 25) & 31u) * 64 + lane];
        f16x2 wa = __builtin_elementwise_min(__builtin_bit_cast(f16x2, g0.x),
                                             __builtin_bit_cast(f16x2, g1.x));
        wa = __builtin_elementwise_min(wa, __builtin_bit_cast(f16x2, g2.x));
        wa = __builtin_elementwise_min(wa, __builtin_bit_cast(f16x2, g3.x));
        wa = __builtin_elementwise_min(wa, __builtin_bit_cast(f16x2, g4.x));
        wa = __builtin_elementwise_min(wa, __builtin_bit_cast(f16x2, g5.x));
        f16x2 wb = __builtin_elementwise_min(__builtin_bit_cast(f16x2, g0.y),
                                             __builtin_bit_cast(f16x2, g1.y));
        wb = __builtin_elementwise_min(wb, __builtin_bit_cast(f16x2, g2.y));
        wb = __builtin_elementwise_min(wb, __builtin_bit_cast(f16x2, g3.y));
        wb = __builtin_elementwise_min(wb, __builtin_bit_cast(f16x2, g4.y));
        wb = __builtin_elementwise_min(wb, __builtin_bit_cast(f16x2, g5.y));
        const float w0 = (float)wa.x, w1 = (float)wa.y;
        const float w2 = (float)wb.x, w3 = (float)wb.y;
        l1[0] += w0; d0[0] += w0 * ox; d1[0] += w0 * oy;
        l1[1] += w1; d0[1] += w1 * ox; d1[1] += w1 * oy;
        l1[2] += w2; d0[2] += w2 * ox; d1[2] += w2 * oy;
        l1[3] += w3; d0[3] += w3 * ox; d1[3] += w3 * oy;
    }
#pragma unroll
    for (int k = 0; k < 4; ++k) {
        pacc[wave][0][lane + 64 * k] = l1[k];
        pacc[wave][1][lane + 64 * k] = d0[k];
        pacc[wave][2][lane + 64 * k] = d1[k];
    }
    __syncthreads();

    // ---- block reduction over 16 waves, 768 active threads ----
    if (t < 3 * ROWS_PB) {
        const int arr = t >> 8;        // 0..2 (l1, d0, d1)
        const int row = t & 255;
        float a = 0.f;
#pragma unroll
        for (int wv = 0; wv < WAVES; ++wv) a += pacc[wv][arr][row];
        partials[(split * 3 + arr) * BATCH + row0 + row] = a;
    }
}

// ---------------------------------------------------------------------------
// Finalize: sum the 8 rule-split partials per row, normalize, tanh, store.
// ---------------------------------------------------------------------------
__global__ void anfis_finalize(const float* __restrict__ partials,
                               const void* __restrict__ mfs_,
                               void* __restrict__ out_) {
    const int row = blockIdx.x * blockDim.x + threadIdx.x;
    if (row >= BATCH) return;
    const bool is_bf16 = (probe_is_bf16(mfs_) != 0);
    float l1 = 0.f, d0 = 0.f, d1 = 0.f;
#pragma unroll
    for (int s = 0; s < SPLITS; ++s) {
        l1 += partials[(s * 3 + 0) * BATCH + row];
        d0 += partials[(s * 3 + 1) * BATCH + row];
        d1 += partials[(s * 3 + 2) * BATCH + row];
    }
    const float inv = 1.0f / fmaxf(l1, 1e-12f);
    const float y0 = tanhf(d0 * inv) * 4.00f + 0.00f;
    const float y1 = tanhf(d1 * inv) * 0.75f + 0.75f;
    if (is_bf16) {
        __hip_bfloat162 o;
        o.x = __float2bfloat16(y0);
        o.y = __float2bfloat16(y1);
        ((__hip_bfloat162*)out_)[row] = o;
    } else {
        ((float2*)out_)[row] = make_float2(y0, y1);
    }
}

extern "C" void kernel_launch(void* const* d_in, const int* in_sizes, int n_in,
                              void* d_out, int out_size, void* d_ws, size_t ws_size,
                              hipStream_t stream) {
    (void)in_sizes; (void)n_in; (void)out_size; (void)ws_size;
    const void* x_   = d_in[0];
    const void* mfc_ = d_in[1];
    const void* mfs_ = d_in[2];
    const void* oc_  = d_in[3];
    const int* input_rules  = (const int*)d_in[4];
    const int* output_rules = (const int*)d_in[5];

    float* parts = (float*)((char*)d_ws + WS_PART_OFF);

    anfis_main<<<ROWGROUPS * SPLITS, THREADS, 0, stream>>>(
        x_, mfc_, mfs_, oc_, input_rules, output_rules, parts);

    anfis_finalize<<<BATCH / 128, 128, 0, stream>>>(parts, mfs_, d_out);
}

// Round 6
// 79.571 us; speedup vs baseline: 1.0259x; 1.0259x over previous
//
#include <hip/hip_runtime.h>
#include <hip/hip_bf16.h>

// Problem constants (JointAnfisNet)
#define BATCH      16384
#define N_IN       6
#define N_MF       5
#define N_FUZZ     30      // N_IN * N_MF
#define N_RULES    2048
#define N_OUT_MEM  12

// Decomposition: 256 rows/block, 4 rows per lane packed as f16x4 (uint2) ->
// one ds_read_b64 serves 4 rows.
// R6 = exact revert to R4 (best measured: 80.0us). R5's bundle (no-xs-staging,
// branch-free probe, wide reduce) measured 81.6 -> regression vs R4; dropping
// xs staging made fuzzify re-read the x window 8x from global, offsetting the
// barrier savings. Budget decomposition (R0..R5 bracket 80.0-81.7):
//   ~40us harness poison fill (84% HBM peak, untouchable)
// + ~18.5us harness restore/gaps (untouchable)
// + ~15-17us main (DS-gather floor ~8.3us + fuzzify ramp + reduce)
// + ~2us finalize. Controllable headroom ~3-5us, below per-round noise.
#define ROWS_PB    256
#define SPLITS     8
#define RULES_PB   (N_RULES / SPLITS)     // 256
#define THREADS    1024
#define WAVES      16
#define RULES_PW   (RULES_PB / WAVES)     // 16
#define ROWGROUPS  (BATCH / ROWS_PB)      // 64

// d_ws layout: partials f32[SPLITS*3*BATCH] = 1.5 MB
#define WS_PART_OFF    0

typedef _Float16 f16x2 __attribute__((ext_vector_type(2)));

// ---------------------------------------------------------------------------
// Deterministic dtype probe: mf_scales is genuinely in [0.5, 1.5]. Interpret
// its first 60 bytes as 30 bf16 halves; all-in-[0.4,1.6] => bf16 data.
// ---------------------------------------------------------------------------
__device__ inline int probe_is_bf16(const void* mfs) {
    const unsigned int* w = (const unsigned int*)mfs;
    int ok = 1;
    for (int k = 0; k < 15; ++k) {
        const unsigned int v = w[k];
        const float lo = __uint_as_float(v << 16);
        const float hi = __uint_as_float(v & 0xffff0000u);
        if (!(lo >= 0.4f && lo <= 1.6f && hi >= 0.4f && hi <= 1.6f)) { ok = 0; break; }
    }
    return ok;
}

// ---------------------------------------------------------------------------
// Main: block = (row group g: 256 rows) x (rule split s: 256 rules).
//   lane (0..63) covers rows {l, l+64, l+128, l+192} packed as f16x4 in uint2.
//   wave (0..15) handles 16 rules. Rule metadata: lanes 0..15 inline-load the
//   raw rule tables and pack; broadcast via readlane at constant j. The inner
//   loop issues ONLY ds_read_b64 (no scalar/global loads -> lgkmcnt tracks
//   just the gathers).
// ---------------------------------------------------------------------------
__global__ __launch_bounds__(THREADS, 4)
void anfis_main(const void* __restrict__ x_,
                const void* __restrict__ mfc_,
                const void* __restrict__ mfs_,
                const void* __restrict__ oc_,
                const int* __restrict__ input_rules,
                const int* __restrict__ output_rules,
                float* __restrict__ partials) {
    __shared__ float xs[ROWS_PB * N_IN];       // 6 KB staged x
    __shared__ float2 cinv[N_FUZZ];            // (center, 1/scale)
    __shared__ uint2 fuzz4[N_FUZZ][64];        // 15 KB, 4 rows/lane as f16x4
    __shared__ float pl1[WAVES][ROWS_PB];      // 16 KB
    __shared__ float pd0[WAVES][ROWS_PB];      // 16 KB
    __shared__ float pd1[WAVES][ROWS_PB];      // 16 KB
    __shared__ int flag;

    const int t     = threadIdx.x;
    const int g     = blockIdx.x >> 3;         // row group 0..63
    const int split = blockIdx.x & 7;          // rule split 0..7
    const int row0  = g * ROWS_PB;

    if (t == 0) flag = probe_is_bf16(mfs_);
    __syncthreads();
    const bool is_bf16 = (flag != 0);

    // ---- per-lane rule-metadata inline load+pack (ex-prep kernel) ----
    const int lane = t & 63;
    const int wave = __builtin_amdgcn_readfirstlane(t >> 6);
    const int rbase = split * RULES_PB + wave * RULES_PW;
    unsigned pk_v = 0u;
    float owx_v = 0.0f, owy_v = 0.0f;
    if (lane < RULES_PW) {
        const int r = rbase + lane;
        const int* rp = input_rules + r * N_IN;     // contiguous 768B per wave
        unsigned p = 0;
#pragma unroll
        for (int i = 0; i < N_IN; ++i) p |= ((unsigned)rp[i] & 31u) << (5 * i);
        pk_v = p;
        const int o0i = output_rules[2 * r + 0];
        const int o1i = output_rules[2 * r + 1];
        if (is_bf16) {
            const unsigned short* oc = (const unsigned short*)oc_;
            owx_v = __uint_as_float((unsigned)oc[o0i] << 16);
            owy_v = __uint_as_float((unsigned)oc[o1i] << 16);
        } else {
            const float* oc = (const float*)oc_;
            owx_v = oc[o0i]; owy_v = oc[o1i];
        }
    }

    // ---- stage x rows + MF params into LDS ----
    if (is_bf16) {
        const unsigned short* xp = (const unsigned short*)x_ + row0 * N_IN;
        for (int i = t; i < ROWS_PB * N_IN; i += THREADS)
            xs[i] = __uint_as_float((unsigned int)xp[i] << 16);
    } else {
        const float* xp = (const float*)x_ + row0 * N_IN;
        for (int i = t; i < ROWS_PB * N_IN; i += THREADS) xs[i] = xp[i];
    }
    if (t < N_FUZZ) {
        float c, s;
        if (is_bf16) {
            c = __uint_as_float((unsigned int)((const unsigned short*)mfc_)[t] << 16);
            s = __uint_as_float((unsigned int)((const unsigned short*)mfs_)[t] << 16);
        } else {
            c = ((const float*)mfc_)[t];
            s = ((const float*)mfs_)[t];
        }
        cinv[t] = make_float2(c, 1.0f / s);
    }
    __syncthreads();

    // ---- fuzzify: 30 x 64 uint2 entries, each = 4 rows' exp(-z^2) as f16 ----
    for (int e = t; e < N_FUZZ * 64; e += THREADS) {
        const int v    = e >> 6;    // MF value index 0..29
        const int ln   = e & 63;
        const int i    = v / N_MF;  // input index
        const float2 ci = cinv[v];
        float f[4];
#pragma unroll
        for (int k = 0; k < 4; ++k) {
            const float z = (xs[(ln + 64 * k) * N_IN + i] - ci.x) * ci.y;
            f[k] = __expf(-z * z);
        }
        f16x2 a = { (_Float16)f[0], (_Float16)f[1] };   // rows ln, ln+64
        f16x2 b = { (_Float16)f[2], (_Float16)f[3] };   // rows ln+128, +192
        uint2 u;
        u.x = __builtin_bit_cast(unsigned int, a);
        u.y = __builtin_bit_cast(unsigned int, b);
        fuzz4[v][ln] = u;
    }
    __syncthreads();

    // ---- rule loop: readlane-broadcast metadata, 6 ds_read_b64 gathers ----
    const uint2* fz = &fuzz4[0][0];

    float l1[4] = {0.f, 0.f, 0.f, 0.f};
    float d0[4] = {0.f, 0.f, 0.f, 0.f};
    float d1[4] = {0.f, 0.f, 0.f, 0.f};

#pragma unroll
    for (int j = 0; j < RULES_PW; ++j) {
        // compile-time lane j -> v_readlane to SGPR; no memory op, no lgkmcnt
        const unsigned p = (unsigned)__builtin_amdgcn_readlane((int)pk_v, j);
        const float ox = __uint_as_float(
            (unsigned)__builtin_amdgcn_readlane((int)__float_as_uint(owx_v), j));
        const float oy = __uint_as_float(
            (unsigned)__builtin_amdgcn_readlane((int)__float_as_uint(owy_v), j));

        const uint2 g0 = fz[((p      ) & 31u) * 64 + lane];
        const uint2 g1 = fz[((p >> 5 ) & 31u) * 64 + lane];
        const uint2 g2 = fz[((p >> 10) & 31u) * 64 + lane];
        const uint2 g3 = fz[((p >> 15) & 31u) * 64 + lane];
        const uint2 g4 = fz[((p >> 20) & 31u) * 64 + lane];
        const uint2 g5 = fz[((p >> 25) & 31u) * 64 + lane];
        f16x2 wa = __builtin_elementwise_min(__builtin_bit_cast(f16x2, g0.x),
                                             __builtin_bit_cast(f16x2, g1.x));
        wa = __builtin_elementwise_min(wa, __builtin_bit_cast(f16x2, g2.x));
        wa = __builtin_elementwise_min(wa, __builtin_bit_cast(f16x2, g3.x));
        wa = __builtin_elementwise_min(wa, __builtin_bit_cast(f16x2, g4.x));
        wa = __builtin_elementwise_min(wa, __builtin_bit_cast(f16x2, g5.x));
        f16x2 wb = __builtin_elementwise_min(__builtin_bit_cast(f16x2, g0.y),
                                             __builtin_bit_cast(f16x2, g1.y));
        wb = __builtin_elementwise_min(wb, __builtin_bit_cast(f16x2, g2.y));
        wb = __builtin_elementwise_min(wb, __builtin_bit_cast(f16x2, g3.y));
        wb = __builtin_elementwise_min(wb, __builtin_bit_cast(f16x2, g4.y));
        wb = __builtin_elementwise_min(wb, __builtin_bit_cast(f16x2, g5.y));
        const float w0 = (float)wa.x, w1 = (float)wa.y;
        const float w2 = (float)wb.x, w3 = (float)wb.y;
        l1[0] += w0; d0[0] += w0 * ox; d1[0] += w0 * oy;
        l1[1] += w1; d0[1] += w1 * ox; d1[1] += w1 * oy;
        l1[2] += w2; d0[2] += w2 * ox; d1[2] += w2 * oy;
        l1[3] += w3; d0[3] += w3 * ox; d1[3] += w3 * oy;
    }
#pragma unroll
    for (int k = 0; k < 4; ++k) {
        pl1[wave][lane + 64 * k] = l1[k];
        pd0[wave][lane + 64 * k] = d0[k];
        pd1[wave][lane + 64 * k] = d1[k];
    }
    __syncthreads();

    // ---- block reduction over 16 waves; write split partials ----
    if (t < ROWS_PB) {
        float a = 0.f, b = 0.f, c = 0.f;
#pragma unroll
        for (int wv = 0; wv < WAVES; ++wv) {
            a += pl1[wv][t];
            b += pd0[wv][t];
            c += pd1[wv][t];
        }
        const int row = row0 + t;
        partials[(split * 3 + 0) * BATCH + row] = a;
        partials[(split * 3 + 1) * BATCH + row] = b;
        partials[(split * 3 + 2) * BATCH + row] = c;
    }
}

// ---------------------------------------------------------------------------
// Finalize: sum the 8 rule-split partials per row, normalize, tanh, store.
// ---------------------------------------------------------------------------
__global__ void anfis_finalize(const float* __restrict__ partials,
                               const void* __restrict__ mfs_,
                               void* __restrict__ out_) {
    __shared__ int flag;
    if (threadIdx.x == 0) flag = probe_is_bf16(mfs_);
    __syncthreads();
    const int row = blockIdx.x * blockDim.x + threadIdx.x;
    if (row >= BATCH) return;
    float l1 = 0.f, d0 = 0.f, d1 = 0.f;
#pragma unroll
    for (int s = 0; s < SPLITS; ++s) {
        l1 += partials[(s * 3 + 0) * BATCH + row];
        d0 += partials[(s * 3 + 1) * BATCH + row];
        d1 += partials[(s * 3 + 2) * BATCH + row];
    }
    const float inv = 1.0f / fmaxf(l1, 1e-12f);
    const float y0 = tanhf(d0 * inv) * 4.00f + 0.00f;
    const float y1 = tanhf(d1 * inv) * 0.75f + 0.75f;
    if (flag) {
        __hip_bfloat162 o;
        o.x = __float2bfloat16(y0);
        o.y = __float2bfloat16(y1);
        ((__hip_bfloat162*)out_)[row] = o;
    } else {
        ((float2*)out_)[row] = make_float2(y0, y1);
    }
}

extern "C" void kernel_launch(void* const* d_in, const int* in_sizes, int n_in,
                              void* d_out, int out_size, void* d_ws, size_t ws_size,
                              hipStream_t stream) {
    (void)in_sizes; (void)n_in; (void)out_size; (void)ws_size;
    const void* x_   = d_in[0];
    const void* mfc_ = d_in[1];
    const void* mfs_ = d_in[2];
    const void* oc_  = d_in[3];
    const int* input_rules  = (const int*)d_in[4];
    const int* output_rules = (const int*)d_in[5];

    float* parts = (float*)((char*)d_ws + WS_PART_OFF);

    anfis_main<<<ROWGROUPS * SPLITS, THREADS, 0, stream>>>(
        x_, mfc_, mfs_, oc_, input_rules, output_rules, parts);

    anfis_finalize<<<BATCH / 256, 256, 0, stream>>>(parts, mfs_, d_out);
}